// Round 3
// baseline (228.744 us; speedup 1.0000x reference)
//
#include <hip/hip_runtime.h>

// NeuralGraphOutput: out[b,o] = sum_a mask[b,a] * relu( sum_f x[b,a,f] * W[f,o] + bias[o] )
//   x[b,a,:] = concat(atoms[b,a,0:64], sum_d bonds[b,a,d,0:16])   (80 features)
//   mask[b,a] = any(edges[b,a,d] != -1)
// B=2048, A=256, D=8, FA=64, FB=16, FP=256
// 1 block = 1 molecule, 512 threads (8 waves -> 24 waves/CU at 3 blocks/CU).
// X[256][100] bf16 in LDS (pitch 100 -> 200B row stride, conflict-free b128 reads),
// W fragments in VGPRs, mfma_f32_16x16x32_bf16, column sums in registers.

#define NB 2048
#define NA 256
#define ND 8
#define NFA 64
#define NFB 16
#define NF 80
#define NFP 256
#define PITCH 100    // LDS row pitch in bf16 elems (K region 0..95 used, 96..99 slack)

typedef __attribute__((ext_vector_type(8))) short short8;   // 8 bf16 = 4 VGPR
typedef __attribute__((ext_vector_type(4))) float f32x4;    // MFMA C/D

static __device__ __forceinline__ unsigned short f2bf(float f) {
    unsigned int u = __float_as_uint(f);
    return (unsigned short)((u + 0x7FFFu + ((u >> 16) & 1u)) >> 16);
}

__launch_bounds__(512, 6)
__global__ void ngf_mfma_kernel(const float4* __restrict__ atoms4,
                                const float4* __restrict__ bonds4,
                                const int4*   __restrict__ edges4,
                                const float*  __restrict__ W,
                                const float*  __restrict__ bias,
                                float* __restrict__ out)
{
    const int b    = blockIdx.x;
    const int tid  = threadIdx.x;    // 0..511
    const int wave = tid >> 6;       // 0..7
    const int lane = tid & 63;
    const int lrow = lane & 15;      // A row / B col / C-D col
    const int lgrp = lane >> 4;      // k-group (A/B) / row-group (C/D)

    __shared__ unsigned short X[NA * PITCH];   // 51200 B
    __shared__ float maskf[NA];                // 1024 B

    const size_t molAtom = (size_t)b * NA;

    // ---------- W as B-fragments in VGPRs (wave owns 32 output cols) ----------
    // B frag layout: col = lane&15, k = ks*32 + (lane>>4)*8 + j ; k>=80 -> 0
    short8 bf[3][2];
    float  bia[2];
    #pragma unroll
    for (int nt = 0; nt < 2; ++nt) {
        const int c = wave * 32 + nt * 16 + lrow;
        bia[nt] = bias[c];
        #pragma unroll
        for (int ks = 0; ks < 3; ++ks) {
            short8 v;
            #pragma unroll
            for (int j = 0; j < 8; ++j) {
                const int k = ks * 32 + lgrp * 8 + j;
                float w = (k < NF) ? W[k * NFP + c] : 0.0f;
                v[j] = (short)f2bf(w);
            }
            bf[ks][nt] = v;
        }
    }

    // ---------- stage X into LDS ----------
    // atoms: 4096 float4, coalesced, 8 per thread
    #pragma unroll
    for (int it = 0; it < 8; ++it) {
        const int flat = it * 512 + tid;
        const int a = flat >> 4, k4 = flat & 15;
        float4 v = atoms4[(molAtom + a) * 16 + k4];
        ushort4 o;
        o.x = f2bf(v.x); o.y = f2bf(v.y); o.z = f2bf(v.z); o.w = f2bf(v.w);
        *(ushort4*)&X[a * PITCH + k4 * 4] = o;
    }
    // bonds: sum over D=8; 4 threads per atom (q = quarter of 16-feature row)
    #pragma unroll
    for (int p = 0; p < 2; ++p) {
        const int a = p * 128 + (tid >> 2);
        const int q = tid & 3;
        const float4* bp = bonds4 + (molAtom + a) * 32 + q;   // atom row = 32 float4
        float4 s = {0.0f, 0.0f, 0.0f, 0.0f};
        #pragma unroll
        for (int d = 0; d < 8; ++d) {
            float4 v = bp[d * 4];
            s.x += v.x; s.y += v.y; s.z += v.z; s.w += v.w;
        }
        ushort4 o;
        o.x = f2bf(s.x); o.y = f2bf(s.y); o.z = f2bf(s.z); o.w = f2bf(s.w);
        *(ushort4*)&X[a * PITCH + NFA + q * 4] = o;
    }
    // edges -> mask; zero the K pad (k=80..95)
    if (tid < NA) {
        const int a = tid;
        int4 e0 = edges4[(molAtom + a) * 2];
        int4 e1 = edges4[(molAtom + a) * 2 + 1];
        bool any = (e0.x != -1) | (e0.y != -1) | (e0.z != -1) | (e0.w != -1)
                 | (e1.x != -1) | (e1.y != -1) | (e1.z != -1) | (e1.w != -1);
        maskf[a] = any ? 1.0f : 0.0f;
        uint4 z = {0u, 0u, 0u, 0u};
        *(uint4*)&X[a * PITCH + 80] = z;
        *(uint4*)&X[a * PITCH + 88] = z;
    }
    __syncthreads();

    // ---------- compute: 16 strips of 16 atoms; every wave reads all strips ----------
    float colsum[2] = {0.0f, 0.0f};
    for (int s = 0; s < 16; ++s) {
        const int row = s * 16 + lrow;
        const unsigned short* xr = &X[row * PITCH + lgrp * 8];
        short8 a0 = *(const short8*)(xr);          // k  0..31 slice
        short8 a1 = *(const short8*)(xr + 32);     // k 32..63 slice
        short8 a2 = *(const short8*)(xr + 64);     // k 64..95 slice (pad zeros)
        float4 m4 = *(const float4*)&maskf[s * 16 + lgrp * 4];
        #pragma unroll
        for (int nt = 0; nt < 2; ++nt) {
            f32x4 acc = {0.0f, 0.0f, 0.0f, 0.0f};
            acc = __builtin_amdgcn_mfma_f32_16x16x32_bf16(a0, bf[0][nt], acc, 0, 0, 0);
            acc = __builtin_amdgcn_mfma_f32_16x16x32_bf16(a1, bf[1][nt], acc, 0, 0, 0);
            acc = __builtin_amdgcn_mfma_f32_16x16x32_bf16(a2, bf[2][nt], acc, 0, 0, 0);
            const float bv = bia[nt];
            colsum[nt] += fmaxf(acc[0] + bv, 0.0f) * m4.x
                        + fmaxf(acc[1] + bv, 0.0f) * m4.y
                        + fmaxf(acc[2] + bv, 0.0f) * m4.z
                        + fmaxf(acc[3] + bv, 0.0f) * m4.w;
        }
    }

    // ---------- reduce over the 4 row-groups and store ----------
    #pragma unroll
    for (int nt = 0; nt < 2; ++nt) {
        float v = colsum[nt];
        v += __shfl_xor(v, 16, 64);
        v += __shfl_xor(v, 32, 64);
        if (lane < 16)
            out[(size_t)b * NFP + wave * 32 + nt * 16 + lane] = v;
    }
}

extern "C" void kernel_launch(void* const* d_in, const int* in_sizes, int n_in,
                              void* d_out, int out_size, void* d_ws, size_t ws_size,
                              hipStream_t stream) {
    const float4* atoms4 = (const float4*)d_in[0];
    const float4* bonds4 = (const float4*)d_in[1];
    const int4*   edges4 = (const int4*)d_in[2];
    const float*  W      = (const float*)d_in[3];
    const float*  bias   = (const float*)d_in[4];
    float* out = (float*)d_out;

    ngf_mfma_kernel<<<NB, 512, 0, stream>>>(atoms4, bonds4, edges4, W, bias, out);
}

// Round 4
// 89.627 us; speedup vs baseline: 2.5522x; 2.5522x over previous
//
#include <hip/hip_runtime.h>

// NeuralGraphOutput: out[b,o] = sum_a mask[b,a] * relu( sum_f x[b,a,f] * W[f,o] + bias[o] )
//   x[b,a,:] = concat(atoms[b,a,0:64], sum_d bonds[b,a,d,0:16])   (80 features)
//   mask[b,a] = any(edges[b,a,d] != -1)
// B=2048, A=256, D=8, FA=64, FB=16, FP=256
//
// R4: half-molecule blocks (4096 x 256thr, LDS 26KB -> 4-5 blocks/CU) so staging
// bursts of co-resident blocks tile each other's compute gaps. W pre-swizzled to
// MFMA B-fragment layout in d_ws by a prep kernel. Partial col-sums to d_ws,
// 2-way reduce kernel. No tight launch_bounds (R3 spill lesson).

#define NB 2048
#define NA 256
#define ND 8
#define NFA 64
#define NFB 16
#define NF 80
#define NFP 256
#define PITCH 100          // bf16 elems per LDS row (200B stride: conflict-free b128)
#define AH 128             // atoms per block (half molecule)

#define WFRAG_BYTES (16 * 3 * 64 * 16)   // [nt][ks][lane] short8 = 48 KB
#define PART_OFF    (64 * 1024)          // partials start at 64KB in ws

typedef __attribute__((ext_vector_type(8))) short short8;   // 8 bf16 = 4 VGPR
typedef __attribute__((ext_vector_type(4))) float f32x4;    // MFMA C/D

static __device__ __forceinline__ unsigned short f2bf(float f) {
    unsigned int u = __float_as_uint(f);
    return (unsigned short)((u + 0x7FFFu + ((u >> 16) & 1u)) >> 16);
}

// ---------- prep: W[80][256] fp32 -> bf16 B-fragments [nt][ks][lane] ----------
__global__ void ngf_prep_w(const float* __restrict__ W, short8* __restrict__ wfrag)
{
    const int gid  = blockIdx.x;        // 0..47 = nt*3 + ks
    const int nt   = gid / 3;
    const int ks   = gid % 3;
    const int lane = threadIdx.x;       // 0..63
    const int c    = nt * 16 + (lane & 15);
    short8 v;
    #pragma unroll
    for (int j = 0; j < 8; ++j) {
        const int k = ks * 32 + (lane >> 4) * 8 + j;
        float w = (k < NF) ? W[k * NFP + c] : 0.0f;
        v[j] = (short)f2bf(w);
    }
    wfrag[gid * 64 + lane] = v;
}

// ---------- main: half molecule per block ----------
__launch_bounds__(256, 4)
__global__ void ngf_mfma_kernel(const float4* __restrict__ atoms4,
                                const float4* __restrict__ bonds4,
                                const int4*   __restrict__ edges4,
                                const short8* __restrict__ wfrag,
                                const float*  __restrict__ bias,
                                float* __restrict__ part)
{
    const int bid  = blockIdx.x;         // 0..4095
    const int tid  = threadIdx.x;        // 0..255
    const int wave = tid >> 6;           // 0..3
    const int lane = tid & 63;
    const int lrow = lane & 15;          // A row / B col / C-D col
    const int lgrp = lane >> 4;          // k-group (A/B) / row-group (C/D)

    __shared__ unsigned short X[AH * PITCH];   // 25600 B
    __shared__ float maskf[AH];                // 512 B

    const size_t atomBase = (size_t)bid * AH;  // == mol*256 + half*128

    // ---------- W fragments: coalesced 16B loads from pre-swizzled ws ----------
    short8 bf[3][4];
    float  bia[4];
    #pragma unroll
    for (int nt = 0; nt < 4; ++nt) {
        const int ntg = wave * 4 + nt;
        bia[nt] = bias[ntg * 16 + lrow];
        #pragma unroll
        for (int ks = 0; ks < 3; ++ks)
            bf[ks][nt] = wfrag[(ntg * 3 + ks) * 64 + lane];
    }

    // ---------- stage X ----------
    // atoms: 128 atoms * 16 float4 = 2048 float4, 8 per thread, coalesced
    #pragma unroll
    for (int it = 0; it < 8; ++it) {
        const int flat = it * 256 + tid;
        const int a = flat >> 4, k4 = flat & 15;
        float4 v = atoms4[(atomBase + a) * 16 + k4];
        ushort4 o;
        o.x = f2bf(v.x); o.y = f2bf(v.y); o.z = f2bf(v.z); o.w = f2bf(v.w);
        *(ushort4*)&X[a * PITCH + k4 * 4] = o;
    }
    // bonds: sum over D=8; 4 threads per atom, 2 passes of 64 atoms
    #pragma unroll
    for (int p = 0; p < 2; ++p) {
        const int a = p * 64 + (tid >> 2);
        const int q = tid & 3;
        const float4* bp = bonds4 + (atomBase + a) * 32 + q;   // atom row = 32 float4
        float4 s = {0.0f, 0.0f, 0.0f, 0.0f};
        #pragma unroll
        for (int d = 0; d < 8; ++d) {
            float4 v = bp[d * 4];
            s.x += v.x; s.y += v.y; s.z += v.z; s.w += v.w;
        }
        ushort4 o;
        o.x = f2bf(s.x); o.y = f2bf(s.y); o.z = f2bf(s.z); o.w = f2bf(s.w);
        *(ushort4*)&X[a * PITCH + NFA + q * 4] = o;
    }
    // edges -> mask; zero K pad (k=80..95)
    if (tid < AH) {
        const int a = tid;
        int4 e0 = edges4[(atomBase + a) * 2];
        int4 e1 = edges4[(atomBase + a) * 2 + 1];
        bool any = (e0.x != -1) | (e0.y != -1) | (e0.z != -1) | (e0.w != -1)
                 | (e1.x != -1) | (e1.y != -1) | (e1.z != -1) | (e1.w != -1);
        maskf[a] = any ? 1.0f : 0.0f;
        uint4 z = {0u, 0u, 0u, 0u};
        *(uint4*)&X[a * PITCH + 80] = z;
        *(uint4*)&X[a * PITCH + 88] = z;
    }
    __syncthreads();

    // ---------- compute: 8 strips of 16 atoms; wave owns 64 output cols ----------
    float colsum[4] = {0.0f, 0.0f, 0.0f, 0.0f};
    #pragma unroll 2
    for (int s = 0; s < 8; ++s) {
        const int row = s * 16 + lrow;
        const unsigned short* xr = &X[row * PITCH + lgrp * 8];
        short8 a0 = *(const short8*)(xr);          // k  0..31
        short8 a1 = *(const short8*)(xr + 32);     // k 32..63
        short8 a2 = *(const short8*)(xr + 64);     // k 64..95 (pad zeros)
        float4 m4 = *(const float4*)&maskf[s * 16 + lgrp * 4];
        #pragma unroll
        for (int nt = 0; nt < 4; ++nt) {
            f32x4 acc = {0.0f, 0.0f, 0.0f, 0.0f};
            acc = __builtin_amdgcn_mfma_f32_16x16x32_bf16(a0, bf[0][nt], acc, 0, 0, 0);
            acc = __builtin_amdgcn_mfma_f32_16x16x32_bf16(a1, bf[1][nt], acc, 0, 0, 0);
            acc = __builtin_amdgcn_mfma_f32_16x16x32_bf16(a2, bf[2][nt], acc, 0, 0, 0);
            const float bv = bia[nt];
            colsum[nt] += fmaxf(acc[0] + bv, 0.0f) * m4.x
                        + fmaxf(acc[1] + bv, 0.0f) * m4.y
                        + fmaxf(acc[2] + bv, 0.0f) * m4.z
                        + fmaxf(acc[3] + bv, 0.0f) * m4.w;
        }
    }

    // ---------- reduce row-groups, store partial ----------
    #pragma unroll
    for (int nt = 0; nt < 4; ++nt) {
        float v = colsum[nt];
        v += __shfl_xor(v, 16, 64);
        v += __shfl_xor(v, 32, 64);
        if (lane < 16)
            part[(size_t)bid * NFP + (wave * 4 + nt) * 16 + lane] = v;
    }
}

// ---------- reduce: out[mol][col] = part[2*mol][col] + part[2*mol+1][col] ----------
__global__ void ngf_reduce(const float* __restrict__ part, float* __restrict__ out)
{
    const int g   = blockIdx.x * 256 + threadIdx.x;   // 0..524287
    const int mol = g >> 8;
    const int col = g & 255;
    out[g] = part[(size_t)(2 * mol) * NFP + col] + part[(size_t)(2 * mol + 1) * NFP + col];
}

extern "C" void kernel_launch(void* const* d_in, const int* in_sizes, int n_in,
                              void* d_out, int out_size, void* d_ws, size_t ws_size,
                              hipStream_t stream) {
    const float4* atoms4 = (const float4*)d_in[0];
    const float4* bonds4 = (const float4*)d_in[1];
    const int4*   edges4 = (const int4*)d_in[2];
    const float*  W      = (const float*)d_in[3];
    const float*  bias   = (const float*)d_in[4];
    float* out = (float*)d_out;

    short8* wfrag = (short8*)d_ws;
    float*  part  = (float*)((char*)d_ws + PART_OFF);   // 4096*256 fp32 = 4 MB

    ngf_prep_w<<<48, 64, 0, stream>>>(W, wfrag);
    ngf_mfma_kernel<<<NB * 2, 256, 0, stream>>>(atoms4, bonds4, edges4, wfrag, bias, part);
    ngf_reduce<<<2048, 256, 0, stream>>>(part, out);
}